// Round 5
// baseline (303.637 us; speedup 1.0000x reference)
//
#include <hip/hip_runtime.h>
#include <hip/hip_bf16.h>

// HMLSTMCell2: B=65536, H=128, gates = 513-wide GEMM (K=384) + pointwise epilogue.
// Gate columns 0..511 via bf16 MFMA 16x16x32; column 512 (sz -> hard threshold z_new)
// in fp64 on the exact scaled fp32 A values. Weights pre-converted to bf16 in d_ws
// (wave-fragment blocked, frag stride 1024 B).
// R7 design: delete the barrier structure entirely. R4/R6 stalled ~70% on the
// per-chunk 8-wave lockstep (barrier + lgkm drain + slowest-wave A-staging chain).
// Each wave is fully private: A fp32 -> registers (2 rows x 8 k-floats/lane = the
// MFMA A-fragment footprint), scale (z in {0,1}, exact), convert via
// v_cvt_pk_bf16_f32 (RNE = old f2bf), W reg-direct from L2 (Wt = 384 KB, resident).
// sz fp64 rides the same regs in the wv==0 wave, reduced with shfl_xor. ZERO
// barriers in the K-loop; NT=256 (4-wave blocks).
// R7->R8 hardening: #pragma unroll 1 on the K-loop. Full unroll + no barriers
// licensed the scheduler to hoist many chunks of A/W loads (48 regs/chunk) ->
// register balloon/spill risk, suspected cause of the R7 container timeout.
// Loop-carried af/wf/av names now pin the pipeline to prefetch distance 1.

#define MT   32          // rows per block
#define NKC  12          // 384 / 32
#define NT   256         // threads per block (4 waves)
#define COFF 8388608     // c_new offset in d_out (65536*128)
#define ZOFF 16777216    // z_new offset (2*65536*128)

using short8 = __attribute__((ext_vector_type(8))) short;  // 8 bf16 (4 VGPR)
using f32x4  = __attribute__((ext_vector_type(4))) float;  // MFMA acc frag

__device__ __forceinline__ unsigned short f2bf(float f) {
  union { float f; unsigned u; } v; v.f = f;
  unsigned r = (v.u + 0x7FFFu + ((v.u >> 16) & 1u)) >> 16;  // RNE truncate
  return (unsigned short)r;
}

__device__ __forceinline__ unsigned cvt_pk_bf16(float lo, float hi) {
  unsigned r;                       // dst[15:0]=bf16(lo), dst[31:16]=bf16(hi), RNE
  asm("v_cvt_pk_bf16_f32 %0, %1, %2" : "=v"(r) : "v"(lo), "v"(hi));
  return r;
}

__device__ __forceinline__ float sigm(float x)     { return 1.f / (1.f + __expf(-x)); }
__device__ __forceinline__ float tanh_fast(float x){ return 1.f - 2.f / (1.f + __expf(2.f * x)); }

// d_ws layout (wave-fragment blocked): short index
//   ((((c*4 + s)*8 + tn)*16 + x)*4 + u)*8 + j
// holds Wc[k = c*32 + u*8 + j][n],  n = (tn>>1)*128 + s*32 + (tn&1)*16 + x,
// Wc = [W; R; U] (cols 0..511). A wave with col-slice s reads frag tn of chunk c
// at byte (c*32768 + s*8192 + tn*1024 + lr*64 + q*16): 1 KB contiguous per load.
__global__ void prep_weights(const float* __restrict__ W, const float* __restrict__ R,
                             const float* __restrict__ U, unsigned short* __restrict__ Wt) {
  int idx = blockIdx.x * blockDim.x + threadIdx.x;   // 0 .. 24575, one 16B unit each
  if (idx >= NKC * 512 * 4) return;
  int u  = idx & 3;            // k unit within chunk
  int x  = (idx >> 2) & 15;    // col within 16-slice
  int tn = (idx >> 6) & 7;     // frag: gate = tn>>1, half = tn&1
  int s  = (idx >> 9) & 3;     // wave col-slice
  int c  = idx >> 11;          // K chunk
  int n  = (tn >> 1) * 128 + s * 32 + (tn & 1) * 16 + x;  // gemm column
  int k0 = c * 32 + u * 8;     // global k of first element
  const float* src; int kb;
  if (k0 < 128)      { src = W; kb = 0;   }
  else if (k0 < 256) { src = R; kb = 128; }
  else               { src = U; kb = 256; }
  const float* colp = src + (size_t)(k0 - kb) * 513 + n;
  unsigned short vs[8];
  #pragma unroll
  for (int j = 0; j < 8; ++j) vs[j] = f2bf(colp[j * 513]);
  uint4 o;
  o.x = (unsigned)vs[0] | ((unsigned)vs[1] << 16);
  o.y = (unsigned)vs[2] | ((unsigned)vs[3] << 16);
  o.z = (unsigned)vs[4] | ((unsigned)vs[5] << 16);
  o.w = (unsigned)vs[6] | ((unsigned)vs[7] << 16);
  reinterpret_cast<uint4*>(Wt)[idx] = o;
}

__global__ __launch_bounds__(NT, 3)
void hmlstm_main(const float* __restrict__ hb, const float* __restrict__ hs,
                 const float* __restrict__ ht, const float* __restrict__ cs,
                 const float* __restrict__ zp, const float* __restrict__ zbp,
                 const float* __restrict__ W,  const float* __restrict__ R,
                 const float* __restrict__ U,  const float* __restrict__ b,
                 const unsigned short* __restrict__ Wt, float* __restrict__ out)
{
  __shared__ float ldsWL[384];                   // fp32 col-512 weights (sz path)

  const int tid  = threadIdx.x;
  const int l    = tid & 63;
  const int wv   = tid >> 6;   // 0..3: 32-H-col slice
  const int q    = l >> 4;     // quad 0..3 = k-unit
  const int lr   = l & 15;
  const int row0 = blockIdx.x * MT;

  for (int k = tid; k < 384; k += NT) {
    ldsWL[k] = (k < 128) ? W[k * 513 + 512]
             : (k < 256) ? R[(k - 128) * 513 + 512]
                         : U[(k - 256) * 513 + 512];
  }
  __syncthreads();                               // the ONLY barrier in this kernel

  // A rows this lane feeds to MFMA: A-operand row = lane&15
  const int r0 = row0 + lr;
  const int r1 = row0 + 16 + lr;
  const float zb0 = zbp[r0], zb1 = zbp[r1];      // all exactly 0.0 or 1.0
  const float zv0 = zp[r0],  zv1 = zp[r1];

  f32x4 acc[2][8];                               // [row 16-group][gate*2+half], 64 AGPR
  {
    f32x4 zf = {0.f, 0.f, 0.f, 0.f};
    #pragma unroll
    for (int i = 0; i < 2; ++i)
      #pragma unroll
      for (int j = 0; j < 8; ++j) acc[i][j] = zf;
  }

  double sz0 = 0.0, sz1 = 0.0;

  const unsigned a0off = (unsigned)r0 * 128 + q * 8;   // float index
  const unsigned a1off = (unsigned)r1 * 128 + q * 8;
  const unsigned woff  = (unsigned)wv * 4096 + lr * 32 + q * 8;  // short index

  f32x4 av[4];                                   // in-flight fp32 A (single buffer)
  short8 af0, af1;                               // current bf16 A fragments

  auto loadA = [&](int c) {
    const float* s = (c < 4) ? hb : (c < 8) ? hs : ht;
    const unsigned ko = (unsigned)(c & 3) * 32;
    av[0] = *(const f32x4*)(s + a0off + ko);
    av[1] = *(const f32x4*)(s + a0off + ko + 4);
    av[2] = *(const f32x4*)(s + a1off + ko);
    av[3] = *(const f32x4*)(s + a1off + ko + 4);
  };
  auto cvtA = [&](int c) {
    f32x4 v0 = av[0], v1 = av[1], v2 = av[2], v3 = av[3];
    if (c < 4)       { v0 *= zb0; v1 *= zb0; v2 *= zb1; v3 *= zb1; }
    else if (c >= 8) { v0 *= zv0; v1 *= zv0; v2 *= zv1; v3 *= zv1; }
    if (wv == 0) {                               // sz: fp64 dot on exact scaled fp32
      const float* wl = ldsWL + c * 32 + q * 8;  // broadcast reads (uniform per q)
      f32x4 w0 = *(const f32x4*)wl;
      f32x4 w1 = *(const f32x4*)(wl + 4);
      sz0 += (double)v0.x * w0.x + (double)v0.y * w0.y + (double)v0.z * w0.z + (double)v0.w * w0.w
           + (double)v1.x * w1.x + (double)v1.y * w1.y + (double)v1.z * w1.z + (double)v1.w * w1.w;
      sz1 += (double)v2.x * w0.x + (double)v2.y * w0.y + (double)v2.z * w0.z + (double)v2.w * w0.w
           + (double)v3.x * w1.x + (double)v3.y * w1.y + (double)v3.z * w1.z + (double)v3.w * w1.w;
    }
    union { unsigned u[4]; short8 s8; } pk0, pk1;
    pk0.u[0] = cvt_pk_bf16(v0.x, v0.y); pk0.u[1] = cvt_pk_bf16(v0.z, v0.w);
    pk0.u[2] = cvt_pk_bf16(v1.x, v1.y); pk0.u[3] = cvt_pk_bf16(v1.z, v1.w);
    pk1.u[0] = cvt_pk_bf16(v2.x, v2.y); pk1.u[1] = cvt_pk_bf16(v2.z, v2.w);
    pk1.u[2] = cvt_pk_bf16(v3.x, v3.y); pk1.u[3] = cvt_pk_bf16(v3.z, v3.w);
    af0 = pk0.s8; af1 = pk1.s8;
  };

  // ---- prologue: chunk 0 A + W in flight, convert on arrival ----
  loadA(0);
  short8 wf[8];
  #pragma unroll
  for (int tn = 0; tn < 8; ++tn)
    wf[tn] = *(const short8*)(Wt + woff + tn * 512);
  cvtA(0);

  // ---- main loop: no barriers; unroll 1 pins pipeline to prefetch distance 1 ----
  #pragma unroll 1
  for (int kc = 0; kc < NKC; ++kc) {
    if (kc < NKC - 1) loadA(kc + 1);             // A(kc+1) rides over the MFMAs
    #pragma unroll
    for (int tn = 0; tn < 8; ++tn) {
      acc[0][tn] = __builtin_amdgcn_mfma_f32_16x16x32_bf16(af0, wf[tn], acc[0][tn], 0, 0, 0);
      acc[1][tn] = __builtin_amdgcn_mfma_f32_16x16x32_bf16(af1, wf[tn], acc[1][tn], 0, 0, 0);
    }
    if (kc < NKC - 1) {
      #pragma unroll
      for (int tn = 0; tn < 8; ++tn)             // W(kc+1): WAR reuse after MFMA issue
        wf[tn] = *(const short8*)(Wt + woff + (kc + 1) * 16384 + tn * 512);
      cvtA(kc + 1);                              // converts as A(kc+1) arrives
    }
  }

  // ---- z_new: q-slice fp64 partials -> shfl_xor reduce, threshold sz > 0 ----
  if (wv == 0) {
    sz0 += __shfl_xor(sz0, 16); sz0 += __shfl_xor(sz0, 32);
    sz1 += __shfl_xor(sz1, 16); sz1 += __shfl_xor(sz1, 32);
    if (l < 16) {
      const float bz = b[512];
      out[ZOFF + r0] = ((float)sz0 + bz > 0.f) ? 1.f : 0.f;
      out[ZOFF + r1] = ((float)sz1 + bz > 0.f) ? 1.f : 0.f;
    }
  }

  // ---- epilogue: wave owns 32 rows x 32 cols; each 128 B out-line written whole ----
  float bias[2][4];
  #pragma unroll
  for (int th = 0; th < 2; ++th) {
    const int col = wv * 32 + th * 16 + lr;
    bias[th][0] = b[col];       bias[th][1] = b[128 + col];
    bias[th][2] = b[256 + col]; bias[th][3] = b[384 + col];
  }
  #pragma unroll
  for (int s = 0; s < 2; ++s) {
    #pragma unroll
    for (int r = 0; r < 4; ++r) {
      const int row = row0 + s * 16 + q * 4 + r;   // C/D: row = quad*4 + reg
      const float zr  = zp[row];
      const float zbr = zbp[row];
      const size_t rowoff = (size_t)row * 128;
      #pragma unroll
      for (int th = 0; th < 2; ++th) {
        const int col = wv * 32 + th * 16 + lr;    // C/D: col = lane&15
        const size_t off = rowoff + col;
        float si = acc[s][0 + th][r] + bias[th][0];
        float sg = acc[s][2 + th][r] + bias[th][1];
        float so = acc[s][4 + th][r] + bias[th][2];
        float sf = acc[s][6 + th][r] + bias[th][3];
        float iv = sigm(si);
        float gv = tanh_fast(sg);
        float ov = sigm(so);
        float fv = sigm(sf);
        float ig = iv * gv;
        float cv = 0.f, hv = 0.f;
        if (zr != 1.f) cv = cs[off];               // row-uniform guard, whole lines
        const bool keep = (zr == 0.f) && (zbr == 0.f);
        if (keep) hv = hs[off];
        float cn = (zr == 1.f) ? ig : ((zbr == 0.f) ? cv : cv * fv + ig);
        float hn = keep ? hv : tanh_fast(cn) * ov;
        out[off]        = hn;
        out[COFF + off] = cn;
      }
    }
  }
}

extern "C" void kernel_launch(void* const* d_in, const int* in_sizes, int n_in,
                              void* d_out, int out_size, void* d_ws, size_t ws_size,
                              hipStream_t stream) {
  const float* hb  = (const float*)d_in[0];
  const float* hs  = (const float*)d_in[1];
  const float* ht  = (const float*)d_in[2];
  const float* cs  = (const float*)d_in[3];
  const float* zp  = (const float*)d_in[4];
  const float* zbp = (const float*)d_in[5];
  const float* W   = (const float*)d_in[6];
  const float* R   = (const float*)d_in[7];
  const float* U   = (const float*)d_in[8];
  const float* b   = (const float*)d_in[9];
  unsigned short* Wt = (unsigned short*)d_ws;   // 12*512*32*2 = 393216 B
  float* out = (float*)d_out;

  prep_weights<<<dim3(96), dim3(256), 0, stream>>>(W, R, U, Wt);
  hmlstm_main<<<dim3(65536 / MT), dim3(NT), 0, stream>>>(
      hb, hs, ht, cs, zp, zbp, W, R, U, b, Wt, out);
}